// Round 14
// baseline (629.677 us; speedup 1.0000x reference)
//
#include <hip/hip_runtime.h>
#include <hip/hip_bf16.h>

typedef __attribute__((ext_vector_type(8))) short short8;
typedef __attribute__((ext_vector_type(4))) float f32x4;
typedef __attribute__((ext_vector_type(4))) unsigned int u32x4;

#define LOG2E 1.44269504088896f
// R14: measurement round — feats/norm/mm amplified REP x (idempotent or 1/REP-scaled),
// stats left at x1 (cost known ~43-45us from R6/R8). Remove for production.
#define REP 8
#define REPSCALE 0.125f

__device__ __forceinline__ float bf2f(unsigned short b) {
    return __uint_as_float(((unsigned)b) << 16);
}
__device__ __forceinline__ unsigned short f2bf(float f) {
    __hip_bfloat16 h = __float2bfloat16(f);
    return __builtin_bit_cast(unsigned short, h);
}

// Kernel 1: seq_fts = x@W1 + b1; emits F1/F2 and Tbp (pre-swizzled, unnormalized).
// Amplified: asm-opaque acc + memory clobber per rep defeat CSE/hoisting.
__global__ __launch_bounds__(256) void k_feats(
    const float* __restrict__ x, const float* __restrict__ W1,
    const float* __restrict__ b1,
    const float* __restrict__ a1, const float* __restrict__ ba1,
    const float* __restrict__ a2, const float* __restrict__ ba2,
    unsigned short* __restrict__ Tbp,
    float* __restrict__ F1, float* __restrict__ F2, int N)
{
    __shared__ float W1s[4096];
    const int t = threadIdx.x, lane = t & 63;
    const int w = __builtin_amdgcn_readfirstlane(t >> 6);
    for (int i = t; i < 1024; i += 256)
        ((float4*)W1s)[i] = ((const float4*)W1)[i];
    __syncthreads();
    float W1r[64];
    #pragma unroll
    for (int c = 0; c < 64; ++c) W1r[c] = W1s[c * 64 + lane];
    const float bias = b1[lane];
    const float a1l = a1[lane], a2l = a2[lane];
    const float bb1 = ba1[0], bb2 = ba2[0];
    const int row0 = (blockIdx.x * 4 + w) * 8;
    const int b = row0 / N, rb = row0 - b * N;
    const int jblk = rb >> 5, kg = (rb >> 3) & 3;
    unsigned short sf[8];
    #pragma unroll 1
    for (int rep = 0; rep < REP; ++rep) {
        asm volatile("" ::: "memory");
        #pragma unroll
        for (int r = 0; r < 8; ++r) {
            const int row = row0 + r;
            const float* __restrict__ xr = x + (size_t)row * 64;
            float acc = bias;
            asm volatile("" : "+v"(acc));   // opaque: forces re-execution per rep
            #pragma unroll
            for (int c = 0; c < 64; ++c) acc = fmaf(xr[c], W1r[c], acc);
            sf[r] = f2bf(acc);
            float r1 = acc * a1l;
            float r2 = acc * a2l;
            #pragma unroll
            for (int off = 32; off; off >>= 1) {
                r1 += __shfl_xor(r1, off);
                r2 += __shfl_xor(r2, off);
            }
            if (lane == 0) {
                F1[row] = LOG2E * (r1 + bb1);
                F2[row] = LOG2E * (r2 + bb2);
            }
        }
        short8 v;
        #pragma unroll
        for (int e = 0; e < 8; ++e) v[e] = (short)sf[e];
        unsigned short* __restrict__ Tp = Tbp + (size_t)b * (N >> 5) * 2048;
        *(short8*)(Tp + ((size_t)(jblk * 4 + (lane >> 4)) * 512 +
                         (kg * 16 + (lane & 15)) * 8)) = v;
    }
}

// Kernel 2: UNCHANGED (x1) — cost known from R6/R8 amplification (~43-45us).
__global__ __launch_bounds__(256) void k_stats(
    const int* __restrict__ adj, const float* __restrict__ F1,
    const float* __restrict__ F2, float* __restrict__ Spart,
    unsigned long long* __restrict__ mask, int N, int BN)
{
    __shared__ unsigned long long lds_mask[64][16];
    const int t = threadIdx.x, lane = t & 63;
    const int w = __builtin_amdgcn_readfirstlane(t >> 6);
    const int b = blockIdx.z;
    const int i0 = blockIdx.x * 64;
    const int jbase = blockIdx.y * 1024 + t * 4;
    const int* __restrict__ adjb = adj + (size_t)b * N * N;
    const float* __restrict__ F2b = F2 + b * N;
    const float4 f1v = *(const float4*)(F1 + b * N + jbase);
    float acc0 = 0.f, acc1 = 0.f, acc2 = 0.f, acc3 = 0.f;
    #pragma unroll 8
    for (int ii = 0; ii < 64; ++ii) {
        const int i = i0 + ii;
        const int4 a = *(const int4*)(adjb + (size_t)i * N + jbase);
        const float f2i = F2b[i];
        const unsigned long long m0 = __ballot(a.x > 0);
        const unsigned long long m1 = __ballot(a.y > 0);
        const unsigned long long m2 = __ballot(a.z > 0);
        const unsigned long long m3 = __ballot(a.w > 0);
        float u, mx;
        u = f1v.x + f2i; mx = fmaxf(u, 0.01f * u);
        acc0 += (a.x > 0) ? __builtin_amdgcn_exp2f(mx) : 0.f;
        u = f1v.y + f2i; mx = fmaxf(u, 0.01f * u);
        acc1 += (a.y > 0) ? __builtin_amdgcn_exp2f(mx) : 0.f;
        u = f1v.z + f2i; mx = fmaxf(u, 0.01f * u);
        acc2 += (a.z > 0) ? __builtin_amdgcn_exp2f(mx) : 0.f;
        u = f1v.w + f2i; mx = fmaxf(u, 0.01f * u);
        acc3 += (a.w > 0) ? __builtin_amdgcn_exp2f(mx) : 0.f;
        if (lane == 0) {
            lds_mask[ii][w * 4 + 0] = m0;
            lds_mask[ii][w * 4 + 1] = m1;
            lds_mask[ii][w * 4 + 2] = m2;
            lds_mask[ii][w * 4 + 3] = m3;
        }
    }
    float4 s4; s4.x = acc0; s4.y = acc1; s4.z = acc2; s4.w = acc3;
    *(float4*)(Spart + (size_t)blockIdx.x * BN + b * N + jbase) = s4;
    __syncthreads();
    {
        const int ii = t >> 2, q = t & 3;
        unsigned long long* __restrict__ maskb = mask + (size_t)b * N * 64;
        unsigned long long* dst = maskb + (size_t)(i0 + ii) * 64 + blockIdx.y * 16 + q * 4;
        const unsigned long long* src = &lds_mask[ii][q * 4];
        dst[0] = src[0]; dst[1] = src[1]; dst[2] = src[2]; dst[3] = src[3];
    }
}

// Kernel 2b: fused reduce+normalize. Amplified idempotently: original Tbp words
// loaded ONCE into regs; each rep recomputes S (memory clobber re-forces loads)
// and stores the same scaled value.
__global__ __launch_bounds__(256) void k_norm(
    const float* __restrict__ Spart, unsigned short* __restrict__ Tbp,
    int N, int BN, int npart)
{
    __shared__ float svp[4][64];
    __shared__ float gl[64];
    const int t = threadIdx.x, pq = t >> 6, jl = t & 63;
    const int jbase = blockIdx.x * 64;
    const int pquarter = npart >> 2;
    const int b = jbase / N;
    const int jblk0 = (jbase - b * N) >> 5;
    unsigned short* __restrict__ Tp = Tbp + (size_t)b * (N >> 5) * 2048;
    unsigned short* ptr_[2];
    int jloc0_[2];
    short8 vorig[2];
    #pragma unroll
    for (int g2 = 0; g2 < 2; ++g2) {
        const int wd = g2 * 256 + t;
        const int jb_l = wd >> 8;
        const int rem = wd & 255;
        const int q = rem >> 6, l = rem & 63;
        jloc0_[g2] = jb_l * 32 + (l >> 4) * 8;
        ptr_[g2] = Tp + ((size_t)(jblk0 + jb_l) * 4 + q) * 512 + l * 8;
        vorig[g2] = *(short8*)ptr_[g2];
    }
    #pragma unroll 1
    for (int rep = 0; rep < REP; ++rep) {
        asm volatile("" ::: "memory");
        float s = 0.f;
        asm volatile("" : "+v"(s));
        for (int k = 0; k < pquarter; ++k)
            s += Spart[(size_t)(pq * pquarter + k) * BN + jbase + jl];
        svp[pq][jl] = s;
        __syncthreads();
        if (t < 64) {
            const float S = svp[0][t] + svp[1][t] + svp[2][t] + svp[3][t];
            gl[t] = S > 0.f ? 1.f / S : 0.f;
        }
        __syncthreads();
        #pragma unroll
        for (int g2 = 0; g2 < 2; ++g2) {
            const short8 v = vorig[g2];
            short8 o;
            #pragma unroll
            for (int e = 0; e < 8; ++e)
                o[e] = (short)f2bf(bf2f((unsigned short)v[e]) * gl[jloc0_[g2] + e]);
            *(short8*)ptr_[g2] = o;
        }
        __syncthreads();
    }
}

__device__ __forceinline__ float wexp(float f1, float F2i) {
    const float u = f1 + F2i;
    const float mx = fmaxf(u, 0.01f * u);
    return __builtin_amdgcn_exp2f(mx);
}

// Kernel 3: out = elu(coefs @ V'). M=32/wave, 8-wave K-split, (512,4), XCD-swizzled.
// Amplified: accs accumulate REP x, scaled by exact 1/REP at write (R8 precedent).
__global__ __launch_bounds__(512, 4) void k_attn_mm(
    const unsigned long long* __restrict__ mask,
    const float* __restrict__ F1, const float* __restrict__ F2,
    const unsigned short* __restrict__ Tbp,
    float* __restrict__ out, int N)
{
    __shared__ float part[8][2048];
    const int t = threadIdx.x, w = t >> 6, l = t & 63;
    const int cpx = gridDim.x >> 3;
    const int d = blockIdx.x;
    const int g = (d & 7) * cpx + (d >> 3);
    const int nblk = N >> 5;
    const int b = g / nblk;
    const int i0 = (g - b * nblk) * 32;
    const int mrow = l & 15;
    const int koff = l >> 4;
    const int iA = i0 + mrow;
    const int iB = i0 + 16 + mrow;
    const float F2iA = F2[b * N + iA];
    const float F2iB = F2[b * N + iB];
    const float* __restrict__ F1b = F1 + b * N;
    const unsigned long long* __restrict__ mrowpA = mask + (size_t)(b * N + iA) * 64;
    const unsigned long long* __restrict__ mrowpB = mask + (size_t)(b * N + iB) * 64;
    const unsigned short* __restrict__ Tp = Tbp + (size_t)b * (N >> 5) * 2048;
    f32x4 accA0 = {0.f, 0.f, 0.f, 0.f}, accA1 = accA0, accA2 = accA0, accA3 = accA0;
    f32x4 accB0 = accA0, accB1 = accA0, accB2 = accA0, accB3 = accA0;
    #pragma unroll 1
    for (int rep = 0; rep < REP; ++rep) {
    #pragma unroll
    for (int kc = 0; kc < 2; ++kc) {
        const int jg = w * 2 + kc;
        const unsigned long long* mwA = mrowpA + jg * 4;
        const unsigned long long* mwB = mrowpB + jg * 4;
        const unsigned long long mA0 = mwA[0], mA1 = mwA[1], mA2 = mwA[2], mA3 = mwA[3];
        const unsigned long long mB0 = mwB[0], mB1 = mwB[1], mB2 = mwB[2], mB3 = mwB[3];
        #pragma unroll
        for (int r = 0; r < 8; ++r) {
            const int j0l = jg * 256 + r * 32 + koff * 8;
            const int sb = r * 8 + koff * 2;
            const float4 fa = *(const float4*)(F1b + j0l);
            const float4 fbv = *(const float4*)(F1b + j0l + 4);
            const float fv[8] = {fa.x, fa.y, fa.z, fa.w, fbv.x, fbv.y, fbv.z, fbv.w};
            const unsigned sA0 = (unsigned)(mA0 >> sb), sA1 = (unsigned)(mA1 >> sb);
            const unsigned sA2 = (unsigned)(mA2 >> sb), sA3 = (unsigned)(mA3 >> sb);
            const unsigned sB0 = (unsigned)(mB0 >> sb), sB1 = (unsigned)(mB1 >> sb);
            const unsigned sB2 = (unsigned)(mB2 >> sb), sB3 = (unsigned)(mB3 >> sb);
            unsigned pA[8], pB[8];
            pA[0] = __float_as_uint(wexp(fv[0], F2iA)) & (0u - (sA0 & 1u));
            pA[1] = __float_as_uint(wexp(fv[1], F2iA)) & (0u - (sA1 & 1u));
            pA[2] = __float_as_uint(wexp(fv[2], F2iA)) & (0u - (sA2 & 1u));
            pA[3] = __float_as_uint(wexp(fv[3], F2iA)) & (0u - (sA3 & 1u));
            pA[4] = __float_as_uint(wexp(fv[4], F2iA)) & (0u - ((sA0 >> 1) & 1u));
            pA[5] = __float_as_uint(wexp(fv[5], F2iA)) & (0u - ((sA1 >> 1) & 1u));
            pA[6] = __float_as_uint(wexp(fv[6], F2iA)) & (0u - ((sA2 >> 1) & 1u));
            pA[7] = __float_as_uint(wexp(fv[7], F2iA)) & (0u - ((sA3 >> 1) & 1u));
            pB[0] = __float_as_uint(wexp(fv[0], F2iB)) & (0u - (sB0 & 1u));
            pB[1] = __float_as_uint(wexp(fv[1], F2iB)) & (0u - (sB1 & 1u));
            pB[2] = __float_as_uint(wexp(fv[2], F2iB)) & (0u - (sB2 & 1u));
            pB[3] = __float_as_uint(wexp(fv[3], F2iB)) & (0u - (sB3 & 1u));
            pB[4] = __float_as_uint(wexp(fv[4], F2iB)) & (0u - ((sB0 >> 1) & 1u));
            pB[5] = __float_as_uint(wexp(fv[5], F2iB)) & (0u - ((sB1 >> 1) & 1u));
            pB[6] = __float_as_uint(wexp(fv[6], F2iB)) & (0u - ((sB2 >> 1) & 1u));
            pB[7] = __float_as_uint(wexp(fv[7], F2iB)) & (0u - ((sB3 >> 1) & 1u));
            u32x4 awA, awB;
            awA.x = __builtin_amdgcn_perm(pA[1], pA[0], 0x07060302u);
            awA.y = __builtin_amdgcn_perm(pA[3], pA[2], 0x07060302u);
            awA.z = __builtin_amdgcn_perm(pA[5], pA[4], 0x07060302u);
            awA.w = __builtin_amdgcn_perm(pA[7], pA[6], 0x07060302u);
            awB.x = __builtin_amdgcn_perm(pB[1], pB[0], 0x07060302u);
            awB.y = __builtin_amdgcn_perm(pB[3], pB[2], 0x07060302u);
            awB.z = __builtin_amdgcn_perm(pB[5], pB[4], 0x07060302u);
            awB.w = __builtin_amdgcn_perm(pB[7], pB[6], 0x07060302u);
            const short8 afA = __builtin_bit_cast(short8, awA);
            const short8 afB = __builtin_bit_cast(short8, awB);
            const unsigned short* tb = Tp + ((size_t)(jg * 8 + r) * 4) * 512 + l * 8;
            const short8 b0 = *(const short8*)(tb);
            const short8 b1 = *(const short8*)(tb + 512);
            const short8 b2 = *(const short8*)(tb + 1024);
            const short8 b3 = *(const short8*)(tb + 1536);
            accA0 = __builtin_amdgcn_mfma_f32_16x16x32_bf16(afA, b0, accA0, 0, 0, 0);
            accA1 = __builtin_amdgcn_mfma_f32_16x16x32_bf16(afA, b1, accA1, 0, 0, 0);
            accA2 = __builtin_amdgcn_mfma_f32_16x16x32_bf16(afA, b2, accA2, 0, 0, 0);
            accA3 = __builtin_amdgcn_mfma_f32_16x16x32_bf16(afA, b3, accA3, 0, 0, 0);
            accB0 = __builtin_amdgcn_mfma_f32_16x16x32_bf16(afB, b0, accB0, 0, 0, 0);
            accB1 = __builtin_amdgcn_mfma_f32_16x16x32_bf16(afB, b1, accB1, 0, 0, 0);
            accB2 = __builtin_amdgcn_mfma_f32_16x16x32_bf16(afB, b2, accB2, 0, 0, 0);
            accB3 = __builtin_amdgcn_mfma_f32_16x16x32_bf16(afB, b3, accB3, 0, 0, 0);
        }
    }
    }
    #pragma unroll
    for (int rgi = 0; rgi < 4; ++rgi) {
        const int m = koff * 4 + rgi;
        part[w][m * 64 + 0 * 16 + mrow] = accA0[rgi] * REPSCALE;
        part[w][m * 64 + 1 * 16 + mrow] = accA1[rgi] * REPSCALE;
        part[w][m * 64 + 2 * 16 + mrow] = accA2[rgi] * REPSCALE;
        part[w][m * 64 + 3 * 16 + mrow] = accA3[rgi] * REPSCALE;
        part[w][(16 + m) * 64 + 0 * 16 + mrow] = accB0[rgi] * REPSCALE;
        part[w][(16 + m) * 64 + 1 * 16 + mrow] = accB1[rgi] * REPSCALE;
        part[w][(16 + m) * 64 + 2 * 16 + mrow] = accB2[rgi] * REPSCALE;
        part[w][(16 + m) * 64 + 3 * 16 + mrow] = accB3[rgi] * REPSCALE;
    }
    __syncthreads();
    const int base = t * 4;
    float4 s = {0.f, 0.f, 0.f, 0.f};
    #pragma unroll
    for (int p = 0; p < 8; ++p) {
        const float4 v = *(const float4*)&part[p][base];
        s.x += v.x; s.y += v.y; s.z += v.z; s.w += v.w;
    }
    float4 r;
    r.x = s.x > 0.f ? s.x : __builtin_amdgcn_exp2f(s.x * LOG2E) - 1.f;
    r.y = s.y > 0.f ? s.y : __builtin_amdgcn_exp2f(s.y * LOG2E) - 1.f;
    r.z = s.z > 0.f ? s.z : __builtin_amdgcn_exp2f(s.z * LOG2E) - 1.f;
    r.w = s.w > 0.f ? s.w : __builtin_amdgcn_exp2f(s.w * LOG2E) - 1.f;
    *(float4*)(out + (size_t)(b * N + i0 + (base >> 6)) * 64 + (base & 63)) = r;
}

extern "C" void kernel_launch(void* const* d_in, const int* in_sizes, int n_in,
                              void* d_out, int out_size, void* d_ws, size_t ws_size,
                              hipStream_t stream) {
    const float* x   = (const float*)d_in[0];
    const int*   adj = (const int*)d_in[1];
    const float* W1  = (const float*)d_in[2];
    const float* b1  = (const float*)d_in[3];
    const float* a1  = (const float*)d_in[4];
    const float* ba1 = (const float*)d_in[5];
    const float* a2  = (const float*)d_in[6];
    const float* ba2 = (const float*)d_in[7];
    float* out = (float*)d_out;

    const int F = in_sizes[3];                       // 64
    const int C = in_sizes[2] / F;                   // 64
    const long xs = in_sizes[0], as = in_sizes[1];
    const int N = (int)(as / (xs / C));              // 4096
    const int B = (int)(xs / ((long)N * C));         // 4
    const int BN = B * N;
    const int npart = N / 64;

    char* p = (char*)d_ws;
    unsigned short* Tbp = (unsigned short*)p; p += (size_t)BN * 64 * 2;
    float* F1 = (float*)p; p += (size_t)BN * 4;
    float* F2 = (float*)p; p += (size_t)BN * 4;
    float* Spart = (float*)p; p += (size_t)npart * BN * 4;
    unsigned long long* mask = (unsigned long long*)p; p += (size_t)BN * 64 * 8;

    k_feats<<<dim3(BN / 32), 256, 0, stream>>>(x, W1, b1, a1, ba1, a2, ba2, Tbp, F1, F2, N);
    k_stats<<<dim3(N / 64, N / 1024, B), 256, 0, stream>>>(adj, F1, F2, Spart, mask, N, BN);
    k_norm<<<dim3(BN / 64), 256, 0, stream>>>(Spart, Tbp, N, BN, npart);
    k_attn_mm<<<dim3(B * (N / 32)), 512, 0, stream>>>(mask, F1, F2, Tbp, out, N);
}

// Round 15
// 107.708 us; speedup vs baseline: 5.8461x; 5.8461x over previous
//
#include <hip/hip_runtime.h>
#include <hip/hip_bf16.h>

typedef __attribute__((ext_vector_type(8))) short short8;
typedef __attribute__((ext_vector_type(4))) float f32x4;
typedef __attribute__((ext_vector_type(4))) unsigned int u32x4;

#define LOG2E 1.44269504088896f

__device__ __forceinline__ float bf2f(unsigned short b) {
    return __uint_as_float(((unsigned)b) << 16);
}
__device__ __forceinline__ unsigned short f2bf(float f) {
    __hip_bfloat16 h = __float2bfloat16(f);
    return __builtin_bit_cast(unsigned short, h);
}

// Kernel 1: seq_fts = x@W1 + b1; emits F1/F2 and Tbp (pre-swizzled MFMA B-fragment
// order, UNNORMALIZED). W1 staged via LDS. UNCHANGED from R13.
__global__ __launch_bounds__(256) void k_feats(
    const float* __restrict__ x, const float* __restrict__ W1,
    const float* __restrict__ b1,
    const float* __restrict__ a1, const float* __restrict__ ba1,
    const float* __restrict__ a2, const float* __restrict__ ba2,
    unsigned short* __restrict__ Tbp,
    float* __restrict__ F1, float* __restrict__ F2, int N)
{
    __shared__ float W1s[4096];
    const int t = threadIdx.x, lane = t & 63;
    const int w = __builtin_amdgcn_readfirstlane(t >> 6);
    for (int i = t; i < 1024; i += 256)
        ((float4*)W1s)[i] = ((const float4*)W1)[i];
    __syncthreads();
    float W1r[64];
    #pragma unroll
    for (int c = 0; c < 64; ++c) W1r[c] = W1s[c * 64 + lane];
    const float bias = b1[lane];
    const float a1l = a1[lane], a2l = a2[lane];
    const float bb1 = ba1[0], bb2 = ba2[0];
    const int row0 = (blockIdx.x * 4 + w) * 8;
    const int b = row0 / N, rb = row0 - b * N;
    const int jblk = rb >> 5, kg = (rb >> 3) & 3;
    unsigned short sf[8];
    #pragma unroll
    for (int r = 0; r < 8; ++r) {
        const int row = row0 + r;
        const float* __restrict__ xr = x + (size_t)row * 64;  // wave-uniform -> s_load
        float acc = bias;
        #pragma unroll
        for (int c = 0; c < 64; ++c) acc = fmaf(xr[c], W1r[c], acc);
        sf[r] = f2bf(acc);
        float r1 = acc * a1l;
        float r2 = acc * a2l;
        #pragma unroll
        for (int off = 32; off; off >>= 1) {
            r1 += __shfl_xor(r1, off);
            r2 += __shfl_xor(r2, off);
        }
        if (lane == 0) {
            F1[row] = LOG2E * (r1 + bb1);
            F2[row] = LOG2E * (r2 + bb2);
        }
    }
    short8 v;
    #pragma unroll
    for (int e = 0; e < 8; ++e) v[e] = (short)sf[e];
    unsigned short* __restrict__ Tp = Tbp + (size_t)b * (N >> 5) * 2048;
    *(short8*)(Tp + ((size_t)(jblk * 4 + (lane >> 4)) * 512 +
                     (kg * 16 + (lane & 15)) * 8)) = v;
}

// Kernel 2: read adj once; bitmask + per-block partial column sums. UNCHANGED.
__global__ __launch_bounds__(256) void k_stats(
    const int* __restrict__ adj, const float* __restrict__ F1,
    const float* __restrict__ F2, float* __restrict__ Spart,
    unsigned long long* __restrict__ mask, int N, int BN)
{
    __shared__ unsigned long long lds_mask[64][16];
    const int t = threadIdx.x, lane = t & 63;
    const int w = __builtin_amdgcn_readfirstlane(t >> 6);
    const int b = blockIdx.z;
    const int i0 = blockIdx.x * 64;
    const int jbase = blockIdx.y * 1024 + t * 4;
    const int* __restrict__ adjb = adj + (size_t)b * N * N;
    const float* __restrict__ F2b = F2 + b * N;
    const float4 f1v = *(const float4*)(F1 + b * N + jbase);
    float acc0 = 0.f, acc1 = 0.f, acc2 = 0.f, acc3 = 0.f;
    #pragma unroll 8
    for (int ii = 0; ii < 64; ++ii) {
        const int i = i0 + ii;
        const int4 a = *(const int4*)(adjb + (size_t)i * N + jbase);
        const float f2i = F2b[i];
        const unsigned long long m0 = __ballot(a.x > 0);
        const unsigned long long m1 = __ballot(a.y > 0);
        const unsigned long long m2 = __ballot(a.z > 0);
        const unsigned long long m3 = __ballot(a.w > 0);
        float u, mx;
        u = f1v.x + f2i; mx = fmaxf(u, 0.01f * u);
        acc0 += (a.x > 0) ? __builtin_amdgcn_exp2f(mx) : 0.f;
        u = f1v.y + f2i; mx = fmaxf(u, 0.01f * u);
        acc1 += (a.y > 0) ? __builtin_amdgcn_exp2f(mx) : 0.f;
        u = f1v.z + f2i; mx = fmaxf(u, 0.01f * u);
        acc2 += (a.z > 0) ? __builtin_amdgcn_exp2f(mx) : 0.f;
        u = f1v.w + f2i; mx = fmaxf(u, 0.01f * u);
        acc3 += (a.w > 0) ? __builtin_amdgcn_exp2f(mx) : 0.f;
        if (lane == 0) {
            lds_mask[ii][w * 4 + 0] = m0;
            lds_mask[ii][w * 4 + 1] = m1;
            lds_mask[ii][w * 4 + 2] = m2;
            lds_mask[ii][w * 4 + 3] = m3;
        }
    }
    float4 s4; s4.x = acc0; s4.y = acc1; s4.z = acc2; s4.w = acc3;
    *(float4*)(Spart + (size_t)blockIdx.x * BN + b * N + jbase) = s4;
    __syncthreads();
    {
        const int ii = t >> 2, q = t & 3;
        unsigned long long* __restrict__ maskb = mask + (size_t)b * N * 64;
        unsigned long long* dst = maskb + (size_t)(i0 + ii) * 64 + blockIdx.y * 16 + q * 4;
        const unsigned long long* src = &lds_mask[ii][q * 4];
        dst[0] = src[0]; dst[1] = src[1]; dst[2] = src[2]; dst[3] = src[3];
    }
}

// Kernel 2b (fused reduce+normalize): B-side fold. UNCHANGED from R13.
__global__ __launch_bounds__(256) void k_norm(
    const float* __restrict__ Spart, unsigned short* __restrict__ Tbp,
    int N, int BN, int npart)
{
    __shared__ float svp[4][64];
    __shared__ float gl[64];
    const int t = threadIdx.x, pq = t >> 6, jl = t & 63;
    const int jbase = blockIdx.x * 64;
    float s = 0.f;
    const int pquarter = npart >> 2;
    for (int k = 0; k < pquarter; ++k)
        s += Spart[(size_t)(pq * pquarter + k) * BN + jbase + jl];
    svp[pq][jl] = s;
    __syncthreads();
    if (t < 64) {
        const float S = svp[0][t] + svp[1][t] + svp[2][t] + svp[3][t];
        gl[t] = S > 0.f ? 1.f / S : 0.f;
    }
    __syncthreads();
    const int b = jbase / N;
    const int jblk0 = (jbase - b * N) >> 5;
    unsigned short* __restrict__ Tp = Tbp + (size_t)b * (N >> 5) * 2048;
    #pragma unroll
    for (int rep = 0; rep < 2; ++rep) {
        const int wd = rep * 256 + t;
        const int jb_l = wd >> 8;
        const int rem = wd & 255;
        const int q = rem >> 6, l = rem & 63;
        const int jloc0 = jb_l * 32 + (l >> 4) * 8;
        unsigned short* ptr = Tp + ((size_t)(jblk0 + jb_l) * 4 + q) * 512 + l * 8;
        short8 v = *(short8*)ptr;
        #pragma unroll
        for (int e = 0; e < 8; ++e)
            v[e] = (short)f2bf(bf2f((unsigned short)v[e]) * gl[jloc0 + e]);
        *(short8*)ptr = v;
    }
}

__device__ __forceinline__ float wexp(float f1, float F2i) {
    const float u = f1 + F2i;
    const float mx = fmaxf(u, 0.01f * u);
    return __builtin_amdgcn_exp2f(mx);
}

// Kernel 3: out = elu(coefs @ V'). M=32/wave, 8-wave K-split, (512,4), XCD-swizzled.
// R15: explicit software pipeline — B-fragments + F1 for iter r+1 load into named
// regs BEFORE r's exp2/perm chain (L2 latency hides under VALU); setprio around MFMA.
__global__ __launch_bounds__(512, 4) void k_attn_mm(
    const unsigned long long* __restrict__ mask,
    const float* __restrict__ F1, const float* __restrict__ F2,
    const unsigned short* __restrict__ Tbp,
    float* __restrict__ out, int N)
{
    __shared__ float part[8][2048];
    const int t = threadIdx.x, w = t >> 6, l = t & 63;
    const int cpx = gridDim.x >> 3;               // grid % 8 == 0
    const int d = blockIdx.x;
    const int g = (d & 7) * cpx + (d >> 3);       // bijective, batch-contiguous per XCD
    const int nblk = N >> 5;
    const int b = g / nblk;
    const int i0 = (g - b * nblk) * 32;
    const int mrow = l & 15;
    const int koff = l >> 4;
    const int iA = i0 + mrow;
    const int iB = i0 + 16 + mrow;
    const float F2iA = F2[b * N + iA];
    const float F2iB = F2[b * N + iB];
    const float* __restrict__ F1b = F1 + b * N;
    const unsigned long long* __restrict__ mrowpA = mask + (size_t)(b * N + iA) * 64;
    const unsigned long long* __restrict__ mrowpB = mask + (size_t)(b * N + iB) * 64;
    const unsigned short* __restrict__ Tp = Tbp + (size_t)b * (N >> 5) * 2048;
    f32x4 accA0 = {0.f, 0.f, 0.f, 0.f}, accA1 = accA0, accA2 = accA0, accA3 = accA0;
    f32x4 accB0 = accA0, accB1 = accA0, accB2 = accA0, accB3 = accA0;
    #pragma unroll
    for (int kc = 0; kc < 2; ++kc) {
        const int jg = w * 2 + kc;                // 256-j group owned by this wave
        const unsigned long long* mwA = mrowpA + jg * 4;
        const unsigned long long* mwB = mrowpB + jg * 4;
        const unsigned long long mA0 = mwA[0], mA1 = mwA[1], mA2 = mwA[2], mA3 = mwA[3];
        const unsigned long long mB0 = mwB[0], mB1 = mwB[1], mB2 = mwB[2], mB3 = mwB[3];
        const unsigned short* tbbase = Tp + ((size_t)(jg * 8) * 4) * 512 + l * 8;
        // prologue: preload r=0 fragments + F1
        short8 nb0 = *(const short8*)(tbbase);
        short8 nb1 = *(const short8*)(tbbase + 512);
        short8 nb2 = *(const short8*)(tbbase + 1024);
        short8 nb3 = *(const short8*)(tbbase + 1536);
        float4 nfa = *(const float4*)(F1b + jg * 256 + koff * 8);
        float4 nfb = *(const float4*)(F1b + jg * 256 + koff * 8 + 4);
        #pragma unroll
        for (int r = 0; r < 8; ++r) {
            const short8 b0 = nb0, b1 = nb1, b2 = nb2, b3 = nb3;
            const float4 fa = nfa, fbv = nfb;
            if (r < 7) {                          // issue r+1 loads before r's VALU chain
                const unsigned short* tbn = tbbase + (size_t)(r + 1) * 2048;
                nb0 = *(const short8*)(tbn);
                nb1 = *(const short8*)(tbn + 512);
                nb2 = *(const short8*)(tbn + 1024);
                nb3 = *(const short8*)(tbn + 1536);
                const int j1 = jg * 256 + (r + 1) * 32 + koff * 8;
                nfa = *(const float4*)(F1b + j1);
                nfb = *(const float4*)(F1b + j1 + 4);
            }
            const int sb = r * 8 + koff * 2;
            const float fv[8] = {fa.x, fa.y, fa.z, fa.w, fbv.x, fbv.y, fbv.z, fbv.w};
            const unsigned sA0 = (unsigned)(mA0 >> sb), sA1 = (unsigned)(mA1 >> sb);
            const unsigned sA2 = (unsigned)(mA2 >> sb), sA3 = (unsigned)(mA3 >> sb);
            const unsigned sB0 = (unsigned)(mB0 >> sb), sB1 = (unsigned)(mB1 >> sb);
            const unsigned sB2 = (unsigned)(mB2 >> sb), sB3 = (unsigned)(mB3 >> sb);
            unsigned pA[8], pB[8];
            pA[0] = __float_as_uint(wexp(fv[0], F2iA)) & (0u - (sA0 & 1u));
            pA[1] = __float_as_uint(wexp(fv[1], F2iA)) & (0u - (sA1 & 1u));
            pA[2] = __float_as_uint(wexp(fv[2], F2iA)) & (0u - (sA2 & 1u));
            pA[3] = __float_as_uint(wexp(fv[3], F2iA)) & (0u - (sA3 & 1u));
            pA[4] = __float_as_uint(wexp(fv[4], F2iA)) & (0u - ((sA0 >> 1) & 1u));
            pA[5] = __float_as_uint(wexp(fv[5], F2iA)) & (0u - ((sA1 >> 1) & 1u));
            pA[6] = __float_as_uint(wexp(fv[6], F2iA)) & (0u - ((sA2 >> 1) & 1u));
            pA[7] = __float_as_uint(wexp(fv[7], F2iA)) & (0u - ((sA3 >> 1) & 1u));
            pB[0] = __float_as_uint(wexp(fv[0], F2iB)) & (0u - (sB0 & 1u));
            pB[1] = __float_as_uint(wexp(fv[1], F2iB)) & (0u - (sB1 & 1u));
            pB[2] = __float_as_uint(wexp(fv[2], F2iB)) & (0u - (sB2 & 1u));
            pB[3] = __float_as_uint(wexp(fv[3], F2iB)) & (0u - (sB3 & 1u));
            pB[4] = __float_as_uint(wexp(fv[4], F2iB)) & (0u - ((sB0 >> 1) & 1u));
            pB[5] = __float_as_uint(wexp(fv[5], F2iB)) & (0u - ((sB1 >> 1) & 1u));
            pB[6] = __float_as_uint(wexp(fv[6], F2iB)) & (0u - ((sB2 >> 1) & 1u));
            pB[7] = __float_as_uint(wexp(fv[7], F2iB)) & (0u - ((sB3 >> 1) & 1u));
            u32x4 awA, awB;
            awA.x = __builtin_amdgcn_perm(pA[1], pA[0], 0x07060302u);
            awA.y = __builtin_amdgcn_perm(pA[3], pA[2], 0x07060302u);
            awA.z = __builtin_amdgcn_perm(pA[5], pA[4], 0x07060302u);
            awA.w = __builtin_amdgcn_perm(pA[7], pA[6], 0x07060302u);
            awB.x = __builtin_amdgcn_perm(pB[1], pB[0], 0x07060302u);
            awB.y = __builtin_amdgcn_perm(pB[3], pB[2], 0x07060302u);
            awB.z = __builtin_amdgcn_perm(pB[5], pB[4], 0x07060302u);
            awB.w = __builtin_amdgcn_perm(pB[7], pB[6], 0x07060302u);
            const short8 afA = __builtin_bit_cast(short8, awA);
            const short8 afB = __builtin_bit_cast(short8, awB);
            __builtin_amdgcn_s_setprio(1);
            accA0 = __builtin_amdgcn_mfma_f32_16x16x32_bf16(afA, b0, accA0, 0, 0, 0);
            accA1 = __builtin_amdgcn_mfma_f32_16x16x32_bf16(afA, b1, accA1, 0, 0, 0);
            accA2 = __builtin_amdgcn_mfma_f32_16x16x32_bf16(afA, b2, accA2, 0, 0, 0);
            accA3 = __builtin_amdgcn_mfma_f32_16x16x32_bf16(afA, b3, accA3, 0, 0, 0);
            accB0 = __builtin_amdgcn_mfma_f32_16x16x32_bf16(afB, b0, accB0, 0, 0, 0);
            accB1 = __builtin_amdgcn_mfma_f32_16x16x32_bf16(afB, b1, accB1, 0, 0, 0);
            accB2 = __builtin_amdgcn_mfma_f32_16x16x32_bf16(afB, b2, accB2, 0, 0, 0);
            accB3 = __builtin_amdgcn_mfma_f32_16x16x32_bf16(afB, b3, accB3, 0, 0, 0);
            __builtin_amdgcn_s_setprio(0);
        }
    }
    #pragma unroll
    for (int rgi = 0; rgi < 4; ++rgi) {
        const int m = koff * 4 + rgi;
        part[w][m * 64 + 0 * 16 + mrow] = accA0[rgi];
        part[w][m * 64 + 1 * 16 + mrow] = accA1[rgi];
        part[w][m * 64 + 2 * 16 + mrow] = accA2[rgi];
        part[w][m * 64 + 3 * 16 + mrow] = accA3[rgi];
        part[w][(16 + m) * 64 + 0 * 16 + mrow] = accB0[rgi];
        part[w][(16 + m) * 64 + 1 * 16 + mrow] = accB1[rgi];
        part[w][(16 + m) * 64 + 2 * 16 + mrow] = accB2[rgi];
        part[w][(16 + m) * 64 + 3 * 16 + mrow] = accB3[rgi];
    }
    __syncthreads();
    const int base = t * 4;                       // 0..2044: 32 rows x 64 f
    float4 s = {0.f, 0.f, 0.f, 0.f};
    #pragma unroll
    for (int p = 0; p < 8; ++p) {
        const float4 v = *(const float4*)&part[p][base];
        s.x += v.x; s.y += v.y; s.z += v.z; s.w += v.w;
    }
    float4 r;
    r.x = s.x > 0.f ? s.x : __builtin_amdgcn_exp2f(s.x * LOG2E) - 1.f;
    r.y = s.y > 0.f ? s.y : __builtin_amdgcn_exp2f(s.y * LOG2E) - 1.f;
    r.z = s.z > 0.f ? s.z : __builtin_amdgcn_exp2f(s.z * LOG2E) - 1.f;
    r.w = s.w > 0.f ? s.w : __builtin_amdgcn_exp2f(s.w * LOG2E) - 1.f;
    *(float4*)(out + (size_t)(b * N + i0 + (base >> 6)) * 64 + (base & 63)) = r;
}

extern "C" void kernel_launch(void* const* d_in, const int* in_sizes, int n_in,
                              void* d_out, int out_size, void* d_ws, size_t ws_size,
                              hipStream_t stream) {
    const float* x   = (const float*)d_in[0];
    const int*   adj = (const int*)d_in[1];
    const float* W1  = (const float*)d_in[2];
    const float* b1  = (const float*)d_in[3];
    const float* a1  = (const float*)d_in[4];
    const float* ba1 = (const float*)d_in[5];
    const float* a2  = (const float*)d_in[6];
    const float* ba2 = (const float*)d_in[7];
    float* out = (float*)d_out;

    const int F = in_sizes[3];                       // 64
    const int C = in_sizes[2] / F;                   // 64
    const long xs = in_sizes[0], as = in_sizes[1];
    const int N = (int)(as / (xs / C));              // 4096
    const int B = (int)(xs / ((long)N * C));         // 4
    const int BN = B * N;
    const int npart = N / 64;

    char* p = (char*)d_ws;
    unsigned short* Tbp = (unsigned short*)p; p += (size_t)BN * 64 * 2;
    float* F1 = (float*)p; p += (size_t)BN * 4;
    float* F2 = (float*)p; p += (size_t)BN * 4;
    float* Spart = (float*)p; p += (size_t)npart * BN * 4;
    unsigned long long* mask = (unsigned long long*)p; p += (size_t)BN * 64 * 8;

    k_feats<<<dim3(BN / 32), 256, 0, stream>>>(x, W1, b1, a1, ba1, a2, ba2, Tbp, F1, F2, N);
    k_stats<<<dim3(N / 64, N / 1024, B), 256, 0, stream>>>(adj, F1, F2, Spart, mask, N, BN);
    k_norm<<<dim3(BN / 64), 256, 0, stream>>>(Spart, Tbp, N, BN, npart);
    k_attn_mm<<<dim3(B * (N / 32)), 512, 0, stream>>>(mask, F1, F2, Tbp, out, N);
}

// Round 16
// 97.561 us; speedup vs baseline: 6.4542x; 1.1040x over previous
//
#include <hip/hip_runtime.h>
#include <hip/hip_bf16.h>

typedef __attribute__((ext_vector_type(8))) short short8;
typedef __attribute__((ext_vector_type(4))) float f32x4;
typedef __attribute__((ext_vector_type(4))) unsigned int u32x4;

#define LOG2E 1.44269504088896f

__device__ __forceinline__ float bf2f(unsigned short b) {
    return __uint_as_float(((unsigned)b) << 16);
}
__device__ __forceinline__ unsigned short f2bf(float f) {
    __hip_bfloat16 h = __float2bfloat16(f);
    return __builtin_bit_cast(unsigned short, h);
}

// Kernel 1: seq_fts = x@W1 + b1; emits F1/F2 and Tbp (pre-swizzled MFMA B-fragment
// order, UNNORMALIZED). W1 staged via LDS (coalesced 16KB load, conflict-free reads).
__global__ __launch_bounds__(256) void k_feats(
    const float* __restrict__ x, const float* __restrict__ W1,
    const float* __restrict__ b1,
    const float* __restrict__ a1, const float* __restrict__ ba1,
    const float* __restrict__ a2, const float* __restrict__ ba2,
    unsigned short* __restrict__ Tbp,
    float* __restrict__ F1, float* __restrict__ F2, int N)
{
    __shared__ float W1s[4096];
    const int t = threadIdx.x, lane = t & 63;
    const int w = __builtin_amdgcn_readfirstlane(t >> 6);
    for (int i = t; i < 1024; i += 256)
        ((float4*)W1s)[i] = ((const float4*)W1)[i];
    __syncthreads();
    float W1r[64];
    #pragma unroll
    for (int c = 0; c < 64; ++c) W1r[c] = W1s[c * 64 + lane];
    const float bias = b1[lane];
    const float a1l = a1[lane], a2l = a2[lane];
    const float bb1 = ba1[0], bb2 = ba2[0];
    const int row0 = (blockIdx.x * 4 + w) * 8;
    const int b = row0 / N, rb = row0 - b * N;
    const int jblk = rb >> 5, kg = (rb >> 3) & 3;
    unsigned short sf[8];
    #pragma unroll
    for (int r = 0; r < 8; ++r) {
        const int row = row0 + r;
        const float* __restrict__ xr = x + (size_t)row * 64;  // wave-uniform -> s_load
        float acc = bias;
        #pragma unroll
        for (int c = 0; c < 64; ++c) acc = fmaf(xr[c], W1r[c], acc);
        sf[r] = f2bf(acc);
        float r1 = acc * a1l;
        float r2 = acc * a2l;
        #pragma unroll
        for (int off = 32; off; off >>= 1) {
            r1 += __shfl_xor(r1, off);
            r2 += __shfl_xor(r2, off);
        }
        if (lane == 0) {
            F1[row] = LOG2E * (r1 + bb1);
            F2[row] = LOG2E * (r2 + bb2);
        }
    }
    short8 v;
    #pragma unroll
    for (int e = 0; e < 8; ++e) v[e] = (short)sf[e];
    unsigned short* __restrict__ Tp = Tbp + (size_t)b * (N >> 5) * 2048;
    *(short8*)(Tp + ((size_t)(jblk * 4 + (lane >> 4)) * 512 +
                     (kg * 16 + (lane & 15)) * 8)) = v;
}

// Kernel 2: read adj once; bitmask + per-block partial column sums (zero atomics).
// mask layout: [b][i][jg(0..15)][c(0..3)] u64; word (jg,c) bit l = adj[b][i][jg*256+4*l+c].
// At ~87% of achievable HBM BW on the 256MB adj stream — memory-roofline-bound.
__global__ __launch_bounds__(256) void k_stats(
    const int* __restrict__ adj, const float* __restrict__ F1,
    const float* __restrict__ F2, float* __restrict__ Spart,
    unsigned long long* __restrict__ mask, int N, int BN)
{
    __shared__ unsigned long long lds_mask[64][16];
    const int t = threadIdx.x, lane = t & 63;
    const int w = __builtin_amdgcn_readfirstlane(t >> 6);
    const int b = blockIdx.z;
    const int i0 = blockIdx.x * 64;
    const int jbase = blockIdx.y * 1024 + t * 4;
    const int* __restrict__ adjb = adj + (size_t)b * N * N;
    const float* __restrict__ F2b = F2 + b * N;
    const float4 f1v = *(const float4*)(F1 + b * N + jbase);
    float acc0 = 0.f, acc1 = 0.f, acc2 = 0.f, acc3 = 0.f;
    #pragma unroll 8
    for (int ii = 0; ii < 64; ++ii) {
        const int i = i0 + ii;
        const int4 a = *(const int4*)(adjb + (size_t)i * N + jbase);
        const float f2i = F2b[i];
        const unsigned long long m0 = __ballot(a.x > 0);
        const unsigned long long m1 = __ballot(a.y > 0);
        const unsigned long long m2 = __ballot(a.z > 0);
        const unsigned long long m3 = __ballot(a.w > 0);
        float u, mx;
        u = f1v.x + f2i; mx = fmaxf(u, 0.01f * u);
        acc0 += (a.x > 0) ? __builtin_amdgcn_exp2f(mx) : 0.f;
        u = f1v.y + f2i; mx = fmaxf(u, 0.01f * u);
        acc1 += (a.y > 0) ? __builtin_amdgcn_exp2f(mx) : 0.f;
        u = f1v.z + f2i; mx = fmaxf(u, 0.01f * u);
        acc2 += (a.z > 0) ? __builtin_amdgcn_exp2f(mx) : 0.f;
        u = f1v.w + f2i; mx = fmaxf(u, 0.01f * u);
        acc3 += (a.w > 0) ? __builtin_amdgcn_exp2f(mx) : 0.f;
        if (lane == 0) {
            lds_mask[ii][w * 4 + 0] = m0;
            lds_mask[ii][w * 4 + 1] = m1;
            lds_mask[ii][w * 4 + 2] = m2;
            lds_mask[ii][w * 4 + 3] = m3;
        }
    }
    float4 s4; s4.x = acc0; s4.y = acc1; s4.z = acc2; s4.w = acc3;
    *(float4*)(Spart + (size_t)blockIdx.x * BN + b * N + jbase) = s4;
    __syncthreads();
    {
        const int ii = t >> 2, q = t & 3;
        unsigned long long* __restrict__ maskb = mask + (size_t)b * N * 64;
        unsigned long long* dst = maskb + (size_t)(i0 + ii) * 64 + blockIdx.y * 16 + q * 4;
        const unsigned long long* src = &lds_mask[ii][q * 4];
        dst[0] = src[0]; dst[1] = src[1]; dst[2] = src[2]; dst[3] = src[3];
    }
}

// Kernel 2b (fused reduce+normalize): per 64-j slice, invS = 1/sum_p Spart, then
// scale the slice's Tbp fragment words in place (B-side fold — the per-j scale
// commutes through the matmul; A-side/exponent folding breaks leaky_relu ordering).
__global__ __launch_bounds__(256) void k_norm(
    const float* __restrict__ Spart, unsigned short* __restrict__ Tbp,
    int N, int BN, int npart)
{
    __shared__ float svp[4][64];
    __shared__ float gl[64];
    const int t = threadIdx.x, pq = t >> 6, jl = t & 63;
    const int jbase = blockIdx.x * 64;
    float s = 0.f;
    const int pquarter = npart >> 2;
    for (int k = 0; k < pquarter; ++k)
        s += Spart[(size_t)(pq * pquarter + k) * BN + jbase + jl];
    svp[pq][jl] = s;
    __syncthreads();
    if (t < 64) {
        const float S = svp[0][t] + svp[1][t] + svp[2][t] + svp[3][t];
        gl[t] = S > 0.f ? 1.f / S : 0.f;
    }
    __syncthreads();
    const int b = jbase / N;
    const int jblk0 = (jbase - b * N) >> 5;
    unsigned short* __restrict__ Tp = Tbp + (size_t)b * (N >> 5) * 2048;
    #pragma unroll
    for (int rep = 0; rep < 2; ++rep) {
        const int wd = rep * 256 + t;          // 0..511: 2 jblks x 256 short8 words
        const int jb_l = wd >> 8;
        const int rem = wd & 255;
        const int q = rem >> 6, l = rem & 63;
        const int jloc0 = jb_l * 32 + (l >> 4) * 8;
        unsigned short* ptr = Tp + ((size_t)(jblk0 + jb_l) * 4 + q) * 512 + l * 8;
        short8 v = *(short8*)ptr;
        #pragma unroll
        for (int e = 0; e < 8; ++e)
            v[e] = (short)f2bf(bf2f((unsigned short)v[e]) * gl[jloc0 + e]);
        *(short8*)ptr = v;
    }
}

__device__ __forceinline__ float wexp(float f1, float F2i) {
    const float u = f1 + F2i;
    const float mx = fmaxf(u, 0.01f * u);
    return __builtin_amdgcn_exp2f(mx);
}

// Kernel 3: out = elu(coefs @ V'). M=32 PER WAVE — b0..b3 loaded once feed TWO
// A-fragments -> B-load instrs halved. 8-wave K-split, grid 512, (512,4) = 4
// waves/SIMD, XCD-swizzled (batch-contiguous per XCD). NOTE: manual software
// pipelining (R15) and 1-block/CU M64 (R9) both REGRESSED — compiler schedule
// + this occupancy is the verified local optimum.
__global__ __launch_bounds__(512, 4) void k_attn_mm(
    const unsigned long long* __restrict__ mask,
    const float* __restrict__ F1, const float* __restrict__ F2,
    const unsigned short* __restrict__ Tbp,
    float* __restrict__ out, int N)
{
    __shared__ float part[8][2048];
    const int t = threadIdx.x, w = t >> 6, l = t & 63;
    const int cpx = gridDim.x >> 3;               // grid % 8 == 0
    const int d = blockIdx.x;
    const int g = (d & 7) * cpx + (d >> 3);       // bijective, batch-contiguous per XCD
    const int nblk = N >> 5;
    const int b = g / nblk;
    const int i0 = (g - b * nblk) * 32;
    const int mrow = l & 15;
    const int koff = l >> 4;
    const int iA = i0 + mrow;
    const int iB = i0 + 16 + mrow;
    const float F2iA = F2[b * N + iA];
    const float F2iB = F2[b * N + iB];
    const float* __restrict__ F1b = F1 + b * N;
    const unsigned long long* __restrict__ mrowpA = mask + (size_t)(b * N + iA) * 64;
    const unsigned long long* __restrict__ mrowpB = mask + (size_t)(b * N + iB) * 64;
    const unsigned short* __restrict__ Tp = Tbp + (size_t)b * (N >> 5) * 2048;
    f32x4 accA0 = {0.f, 0.f, 0.f, 0.f}, accA1 = accA0, accA2 = accA0, accA3 = accA0;
    f32x4 accB0 = accA0, accB1 = accA0, accB2 = accA0, accB3 = accA0;
    #pragma unroll
    for (int kc = 0; kc < 2; ++kc) {
        const int jg = w * 2 + kc;                // 256-j group owned by this wave
        const unsigned long long* mwA = mrowpA + jg * 4;
        const unsigned long long* mwB = mrowpB + jg * 4;
        const unsigned long long mA0 = mwA[0], mA1 = mwA[1], mA2 = mwA[2], mA3 = mwA[3];
        const unsigned long long mB0 = mwB[0], mB1 = mwB[1], mB2 = mwB[2], mB3 = mwB[3];
        #pragma unroll
        for (int r = 0; r < 8; ++r) {
            const int j0l = jg * 256 + r * 32 + koff * 8;
            const int sb = r * 8 + koff * 2;
            const float4 fa = *(const float4*)(F1b + j0l);
            const float4 fbv = *(const float4*)(F1b + j0l + 4);
            const float fv[8] = {fa.x, fa.y, fa.z, fa.w, fbv.x, fbv.y, fbv.z, fbv.w};
            const unsigned sA0 = (unsigned)(mA0 >> sb), sA1 = (unsigned)(mA1 >> sb);
            const unsigned sA2 = (unsigned)(mA2 >> sb), sA3 = (unsigned)(mA3 >> sb);
            const unsigned sB0 = (unsigned)(mB0 >> sb), sB1 = (unsigned)(mB1 >> sb);
            const unsigned sB2 = (unsigned)(mB2 >> sb), sB3 = (unsigned)(mB3 >> sb);
            unsigned pA[8], pB[8];
            pA[0] = __float_as_uint(wexp(fv[0], F2iA)) & (0u - (sA0 & 1u));
            pA[1] = __float_as_uint(wexp(fv[1], F2iA)) & (0u - (sA1 & 1u));
            pA[2] = __float_as_uint(wexp(fv[2], F2iA)) & (0u - (sA2 & 1u));
            pA[3] = __float_as_uint(wexp(fv[3], F2iA)) & (0u - (sA3 & 1u));
            pA[4] = __float_as_uint(wexp(fv[4], F2iA)) & (0u - ((sA0 >> 1) & 1u));
            pA[5] = __float_as_uint(wexp(fv[5], F2iA)) & (0u - ((sA1 >> 1) & 1u));
            pA[6] = __float_as_uint(wexp(fv[6], F2iA)) & (0u - ((sA2 >> 1) & 1u));
            pA[7] = __float_as_uint(wexp(fv[7], F2iA)) & (0u - ((sA3 >> 1) & 1u));
            pB[0] = __float_as_uint(wexp(fv[0], F2iB)) & (0u - (sB0 & 1u));
            pB[1] = __float_as_uint(wexp(fv[1], F2iB)) & (0u - (sB1 & 1u));
            pB[2] = __float_as_uint(wexp(fv[2], F2iB)) & (0u - (sB2 & 1u));
            pB[3] = __float_as_uint(wexp(fv[3], F2iB)) & (0u - (sB3 & 1u));
            pB[4] = __float_as_uint(wexp(fv[4], F2iB)) & (0u - ((sB0 >> 1) & 1u));
            pB[5] = __float_as_uint(wexp(fv[5], F2iB)) & (0u - ((sB1 >> 1) & 1u));
            pB[6] = __float_as_uint(wexp(fv[6], F2iB)) & (0u - ((sB2 >> 1) & 1u));
            pB[7] = __float_as_uint(wexp(fv[7], F2iB)) & (0u - ((sB3 >> 1) & 1u));
            u32x4 awA, awB;
            awA.x = __builtin_amdgcn_perm(pA[1], pA[0], 0x07060302u);
            awA.y = __builtin_amdgcn_perm(pA[3], pA[2], 0x07060302u);
            awA.z = __builtin_amdgcn_perm(pA[5], pA[4], 0x07060302u);
            awA.w = __builtin_amdgcn_perm(pA[7], pA[6], 0x07060302u);
            awB.x = __builtin_amdgcn_perm(pB[1], pB[0], 0x07060302u);
            awB.y = __builtin_amdgcn_perm(pB[3], pB[2], 0x07060302u);
            awB.z = __builtin_amdgcn_perm(pB[5], pB[4], 0x07060302u);
            awB.w = __builtin_amdgcn_perm(pB[7], pB[6], 0x07060302u);
            const short8 afA = __builtin_bit_cast(short8, awA);
            const short8 afB = __builtin_bit_cast(short8, awB);
            const unsigned short* tb = Tp + ((size_t)(jg * 8 + r) * 4) * 512 + l * 8;
            const short8 b0 = *(const short8*)(tb);
            const short8 b1 = *(const short8*)(tb + 512);
            const short8 b2 = *(const short8*)(tb + 1024);
            const short8 b3 = *(const short8*)(tb + 1536);
            accA0 = __builtin_amdgcn_mfma_f32_16x16x32_bf16(afA, b0, accA0, 0, 0, 0);
            accA1 = __builtin_amdgcn_mfma_f32_16x16x32_bf16(afA, b1, accA1, 0, 0, 0);
            accA2 = __builtin_amdgcn_mfma_f32_16x16x32_bf16(afA, b2, accA2, 0, 0, 0);
            accA3 = __builtin_amdgcn_mfma_f32_16x16x32_bf16(afA, b3, accA3, 0, 0, 0);
            accB0 = __builtin_amdgcn_mfma_f32_16x16x32_bf16(afB, b0, accB0, 0, 0, 0);
            accB1 = __builtin_amdgcn_mfma_f32_16x16x32_bf16(afB, b1, accB1, 0, 0, 0);
            accB2 = __builtin_amdgcn_mfma_f32_16x16x32_bf16(afB, b2, accB2, 0, 0, 0);
            accB3 = __builtin_amdgcn_mfma_f32_16x16x32_bf16(afB, b3, accB3, 0, 0, 0);
        }
    }
    #pragma unroll
    for (int rgi = 0; rgi < 4; ++rgi) {
        const int m = koff * 4 + rgi;
        part[w][m * 64 + 0 * 16 + mrow] = accA0[rgi];
        part[w][m * 64 + 1 * 16 + mrow] = accA1[rgi];
        part[w][m * 64 + 2 * 16 + mrow] = accA2[rgi];
        part[w][m * 64 + 3 * 16 + mrow] = accA3[rgi];
        part[w][(16 + m) * 64 + 0 * 16 + mrow] = accB0[rgi];
        part[w][(16 + m) * 64 + 1 * 16 + mrow] = accB1[rgi];
        part[w][(16 + m) * 64 + 2 * 16 + mrow] = accB2[rgi];
        part[w][(16 + m) * 64 + 3 * 16 + mrow] = accB3[rgi];
    }
    __syncthreads();
    const int base = t * 4;                       // 0..2044: 32 rows x 64 f
    float4 s = {0.f, 0.f, 0.f, 0.f};
    #pragma unroll
    for (int p = 0; p < 8; ++p) {
        const float4 v = *(const float4*)&part[p][base];
        s.x += v.x; s.y += v.y; s.z += v.z; s.w += v.w;
    }
    float4 r;
    r.x = s.x > 0.f ? s.x : __builtin_amdgcn_exp2f(s.x * LOG2E) - 1.f;
    r.y = s.y > 0.f ? s.y : __builtin_amdgcn_exp2f(s.y * LOG2E) - 1.f;
    r.z = s.z > 0.f ? s.z : __builtin_amdgcn_exp2f(s.z * LOG2E) - 1.f;
    r.w = s.w > 0.f ? s.w : __builtin_amdgcn_exp2f(s.w * LOG2E) - 1.f;
    *(float4*)(out + (size_t)(b * N + i0 + (base >> 6)) * 64 + (base & 63)) = r;
}

extern "C" void kernel_launch(void* const* d_in, const int* in_sizes, int n_in,
                              void* d_out, int out_size, void* d_ws, size_t ws_size,
                              hipStream_t stream) {
    const float* x   = (const float*)d_in[0];
    const int*   adj = (const int*)d_in[1];
    const float* W1  = (const float*)d_in[2];
    const float* b1  = (const float*)d_in[3];
    const float* a1  = (const float*)d_in[4];
    const float* ba1 = (const float*)d_in[5];
    const float* a2  = (const float*)d_in[6];
    const float* ba2 = (const float*)d_in[7];
    float* out = (float*)d_out;

    const int F = in_sizes[3];                       // 64
    const int C = in_sizes[2] / F;                   // 64
    const long xs = in_sizes[0], as = in_sizes[1];
    const int N = (int)(as / (xs / C));              // 4096
    const int B = (int)(xs / ((long)N * C));         // 4
    const int BN = B * N;
    const int npart = N / 64;

    char* p = (char*)d_ws;
    unsigned short* Tbp = (unsigned short*)p; p += (size_t)BN * 64 * 2;
    float* F1 = (float*)p; p += (size_t)BN * 4;
    float* F2 = (float*)p; p += (size_t)BN * 4;
    float* Spart = (float*)p; p += (size_t)npart * BN * 4;
    unsigned long long* mask = (unsigned long long*)p; p += (size_t)BN * 64 * 8;

    k_feats<<<dim3(BN / 32), 256, 0, stream>>>(x, W1, b1, a1, ba1, a2, ba2, Tbp, F1, F2, N);
    k_stats<<<dim3(N / 64, N / 1024, B), 256, 0, stream>>>(adj, F1, F2, Spart, mask, N, BN);
    k_norm<<<dim3(BN / 64), 256, 0, stream>>>(Spart, Tbp, N, BN, npart);
    k_attn_mm<<<dim3(B * (N / 32)), 512, 0, stream>>>(mask, F1, F2, Tbp, out, N);
}